// Round 14
// baseline (254.389 us; speedup 1.0000x reference)
//
#include <hip/hip_runtime.h>
#include <math.h>

// B=4, S=2048, E=1024, H=16, D=64
constexpr int Bn = 4;
constexpr int Sn = 2048;
constexpr int En = 1024;
constexpr int Hn = 16;
constexpr int Dn = 64;

typedef float f32x4 __attribute__((ext_vector_type(4)));
typedef short s16x8 __attribute__((ext_vector_type(8)));
typedef short s16x4 __attribute__((ext_vector_type(4)));

__device__ __forceinline__ short f2bf(float f) {
    unsigned u = __builtin_bit_cast(unsigned, f);
    unsigned r = (u + 0x7fffu + ((u >> 16) & 1u)) >> 16;
    return (short)r;
}

// pack two f32 -> two bf16 (RNE) in one VALU op
__device__ __forceinline__ unsigned cvt_pk_bf16(float lo, float hi) {
    unsigned r;
    asm("v_cvt_pk_bf16_f32 %0, %1, %2" : "=v"(r) : "v"(lo), "v"(hi));
    return r;
}

// async global->LDS, 16B per lane; LDS dest = wave-uniform base + lane*16
__device__ __forceinline__ void glds16(const short* g, short* l) {
    __builtin_amdgcn_global_load_lds(
        (const __attribute__((address_space(1))) short*)g,
        (__attribute__((address_space(3))) short*)l, 16, 0, 0);
}

// ---------------------------------------------------------------------------
// Fused prep kernel: one dispatch replaces conv_x / build_wcat / conv_wo.
// Blocks [0,8192): x f32 -> bf16. [8192,8960): Wcat transpose. [8960,9984): Wo.
// ---------------------------------------------------------------------------
__global__ __launch_bounds__(256) void prep_kernel(
    const float* __restrict__ x, short* __restrict__ y,
    const float* __restrict__ Wq, const float* __restrict__ bq,
    const float* __restrict__ Wk, const float* __restrict__ bk,
    const float* __restrict__ Wv, const float* __restrict__ bv,
    short* __restrict__ Wcat, float* __restrict__ bias_cat,
    const float* __restrict__ Wo, short* __restrict__ Wob)
{
    const int bid = blockIdx.x;
    const int tid = threadIdx.x;

    if (bid < 8192) {
        // conv_x
        size_t i = ((size_t)bid * 256 + tid) * 4;
        float4 v = *(const float4*)(x + i);
        s16x4 o;
        o[0] = f2bf(v.x); o[1] = f2bf(v.y); o[2] = f2bf(v.z); o[3] = f2bf(v.w);
        *(s16x4*)(y + i) = o;
    } else if (bid < 8960) {
        // build_wcat: j = et + h*16 + p*256
        const int j  = bid - 8192;
        const int et = j & 15, h = (j >> 4) & 15, p = j >> 8;
        const float* W  = (p == 0) ? Wq : (p == 1) ? Wk : Wv;
        const float* bb = (p == 0) ? bq : (p == 1) ? bk : bv;
        const float* Wh = W + (size_t)h * En * Dn;

        __shared__ float T[64][65];
        #pragma unroll
        for (int it = 0; it < 16; it++) {
            int idx = tid + it * 256;
            int e = idx >> 6, d = idx & 63;
            T[d][e] = Wh[(size_t)(et * 64 + e) * Dn + d];
        }
        __syncthreads();
        #pragma unroll
        for (int it = 0; it < 16; it++) {
            int idx = tid + it * 256;
            int d = idx >> 6, e = idx & 63;
            Wcat[(size_t)(p * 1024 + h * 64 + d) * En + et * 64 + e] = f2bf(T[d][e]);
        }
        if (et == 0 && tid < 64)
            bias_cat[p * 1024 + h * 64 + tid] = bb[h * 64 + tid];
    } else {
        // conv_wo
        const size_t base = (size_t)(bid - 8960) * En;
        #pragma unroll
        for (int i = 0; i < 4; i++) {
            int k = tid + i * 256;
            Wob[base + k] = f2bf(Wo[base + k]);
        }
    }
}

// ---------------------------------------------------------------------------
// bf16 MFMA GEMM: C[M x N] = A[M x 1024] @ Bt[N x 1024]^T (+ bias)
// 256x128 tile, 8 waves (512 thr), BK=64, global_load_lds, XOR-swizzled LDS.
// Each wave: 64x64 subtile (wr = (w>>1)*64 in M, wc = (w&1)*64 in N).
// mode 0: fp32 out + bias. mode 1: QKV epilogue (Q scaled by log2e/8; V packed).
// ---------------------------------------------------------------------------
__global__ __launch_bounds__(512) void gemm_bt_kernel(
    const short* __restrict__ A,
    const short* __restrict__ Bt,
    const float* __restrict__ bias,
    float* __restrict__ outF,
    short* __restrict__ Qb, short* __restrict__ Kb, short* __restrict__ Vtb,
    int mode)
{
    constexpr int K = En;
    const int m0 = blockIdx.x * 256;
    const int n0 = blockIdx.y * 128;

    __shared__ short As[256 * 64];   // 32 KB
    __shared__ short Bs[128 * 64];   // 16 KB

    const int tid  = threadIdx.x;
    const int w    = tid >> 6;       // 0..7
    const int lane = tid & 63;
    const int quad = lane >> 4;
    const int l15  = lane & 15;
    const int wr = (w >> 1) * 64;    // 0,64,128,192
    const int wc = (w & 1) * 64;     // 0,64

    f32x4 acc[4][4];
    #pragma unroll
    for (int i = 0; i < 4; i++)
        #pragma unroll
        for (int j = 0; j < 4; j++)
            #pragma unroll
            for (int e = 0; e < 4; e++) acc[i][j][e] = 0.f;

    for (int k0 = 0; k0 < K; k0 += 64) {
        // A: 256 rows x 64 shorts = 2048 chunks; 4 wave-issues per wave
        #pragma unroll
        for (int r = 0; r < 4; r++) {
            int c   = (r * 8 + w) * 64 + lane;
            int row = c >> 3;
            int lp  = (c & 7) ^ (row & 7);
            glds16(A + (size_t)(m0 + row) * K + k0 + lp * 8,
                   As + (r * 8 + w) * 512);
        }
        // B: 128 rows = 1024 chunks; 2 wave-issues per wave
        #pragma unroll
        for (int r = 0; r < 2; r++) {
            int c   = (r * 8 + w) * 64 + lane;
            int row = c >> 3;
            int lp  = (c & 7) ^ (row & 7);
            glds16(Bt + (size_t)(n0 + row) * K + k0 + lp * 8,
                   Bs + (r * 8 + w) * 512);
        }
        __syncthreads();

        #pragma unroll
        for (int ks = 0; ks < 2; ks++) {
            s16x8 af[4], bfr[4];
            #pragma unroll
            for (int mt = 0; mt < 4; mt++) {
                int row = wr + mt * 16 + l15;
                af[mt] = *(const s16x8*)&As[row * 64 + (((ks * 4 + quad) ^ (l15 & 7)) * 8)];
            }
            #pragma unroll
            for (int nt = 0; nt < 4; nt++) {
                int row = wc + nt * 16 + l15;
                bfr[nt] = *(const s16x8*)&Bs[row * 64 + (((ks * 4 + quad) ^ (l15 & 7)) * 8)];
            }
            #pragma unroll
            for (int mt = 0; mt < 4; mt++)
                #pragma unroll
                for (int nt = 0; nt < 4; nt++)
                    acc[mt][nt] = __builtin_amdgcn_mfma_f32_16x16x32_bf16(
                        af[mt], bfr[nt], acc[mt][nt], 0, 0, 0);
        }
        __syncthreads();
    }

    if (mode == 0) {
        #pragma unroll
        for (int mt = 0; mt < 4; mt++) {
            #pragma unroll
            for (int reg = 0; reg < 4; reg++) {
                int m = m0 + wr + mt * 16 + quad * 4 + reg;
                #pragma unroll
                for (int nt = 0; nt < 4; nt++) {
                    int n = n0 + wc + nt * 16 + l15;
                    outF[(size_t)m * En + n] = acc[mt][nt][reg] + bias[n];
                }
            }
        }
    } else {
        const int p = (n0 + wc) >> 10;   // uniform over 64-wide wave tile
        if (p < 2) {
            // fold 1/sqrt(D) AND log2(e) into Q so attn can use exp2 directly
            const float qs = (p == 0) ? 0.125f * 1.44269504088896f : 1.0f;
            short* dst = (p == 0) ? Qb : Kb;
            #pragma unroll
            for (int mt = 0; mt < 4; mt++) {
                #pragma unroll
                for (int reg = 0; reg < 4; reg++) {
                    int m = m0 + wr + mt * 16 + quad * 4 + reg;
                    int b = m >> 11, s = m & 2047;
                    #pragma unroll
                    for (int nt = 0; nt < 4; nt++) {
                        int n = n0 + wc + nt * 16 + l15;
                        int h = (n >> 6) & 15, d = n & 63;
                        dst[(((size_t)(b * Hn + h)) * Sn + s) * Dn + d] =
                            f2bf((acc[mt][nt][reg] + bias[n]) * qs);
                    }
                }
            }
        } else {
            // V: regs 0..3 are contiguous in s -> one 8B store per (mt,nt)
            #pragma unroll
            for (int mt = 0; mt < 4; mt++) {
                int m = m0 + wr + mt * 16 + quad * 4;   // reg 0; same b for all 4
                int b = m >> 11, s = m & 2047;
                #pragma unroll
                for (int nt = 0; nt < 4; nt++) {
                    int n = n0 + wc + nt * 16 + l15;
                    int h = (n >> 6) & 15, d = n & 63;
                    s16x4 pk;
                    #pragma unroll
                    for (int reg = 0; reg < 4; reg++)
                        pk[reg] = f2bf(acc[mt][nt][reg] + bias[n]);
                    *(s16x4*)(Vtb + (((size_t)(b * Hn + h)) * Dn + d) * Sn + s) = pk;
                }
            }
        }
    }
}

// ---------------------------------------------------------------------------
// Out-projection GEMM: 128x128 tile, 512 thr (8 waves x 32x64 subtile).
// EXACT r8 version (best measured total). NO pin (natural ~70 VGPR; r10
// proved pinning past natural use spills). Do not touch.
// ---------------------------------------------------------------------------
__global__ __launch_bounds__(512) void gemm_bt_out_kernel(
    const short* __restrict__ A,
    const short* __restrict__ Bt,
    const float* __restrict__ bias,
    float* __restrict__ outF)
{
    constexpr int K = En;
    const int m0 = blockIdx.x * 128;
    const int n0 = blockIdx.y * 128;

    __shared__ short As[128 * 64];   // 16 KB
    __shared__ short Bs[128 * 64];   // 16 KB

    const int tid  = threadIdx.x;
    const int w    = tid >> 6;       // 0..7
    const int lane = tid & 63;
    const int quad = lane >> 4;
    const int l15  = lane & 15;
    const int wr = (w >> 1) * 32;    // 0,32,64,96
    const int wc = (w & 1) * 64;     // 0,64

    f32x4 acc[2][4];
    #pragma unroll
    for (int i = 0; i < 2; i++)
        #pragma unroll
        for (int j = 0; j < 4; j++)
            #pragma unroll
            for (int e = 0; e < 4; e++) acc[i][j][e] = 0.f;

    for (int k0 = 0; k0 < K; k0 += 64) {
        // A: 128 rows x 64 shorts = 1024 chunks; 2 wave-issues per wave
        #pragma unroll
        for (int r = 0; r < 2; r++) {
            int c   = (r * 8 + w) * 64 + lane;
            int row = c >> 3;
            int lp  = (c & 7) ^ (row & 7);
            glds16(A + (size_t)(m0 + row) * K + k0 + lp * 8,
                   As + (r * 8 + w) * 512);
        }
        // B: 128 rows = 1024 chunks; 2 wave-issues per wave
        #pragma unroll
        for (int r = 0; r < 2; r++) {
            int c   = (r * 8 + w) * 64 + lane;
            int row = c >> 3;
            int lp  = (c & 7) ^ (row & 7);
            glds16(Bt + (size_t)(n0 + row) * K + k0 + lp * 8,
                   Bs + (r * 8 + w) * 512);
        }
        __syncthreads();

        #pragma unroll
        for (int ks = 0; ks < 2; ks++) {
            s16x8 af[2], bfr[4];
            #pragma unroll
            for (int mt = 0; mt < 2; mt++) {
                int row = wr + mt * 16 + l15;
                af[mt] = *(const s16x8*)&As[row * 64 + (((ks * 4 + quad) ^ (l15 & 7)) * 8)];
            }
            #pragma unroll
            for (int nt = 0; nt < 4; nt++) {
                int row = wc + nt * 16 + l15;
                bfr[nt] = *(const s16x8*)&Bs[row * 64 + (((ks * 4 + quad) ^ (l15 & 7)) * 8)];
            }
            #pragma unroll
            for (int mt = 0; mt < 2; mt++)
                #pragma unroll
                for (int nt = 0; nt < 4; nt++)
                    acc[mt][nt] = __builtin_amdgcn_mfma_f32_16x16x32_bf16(
                        af[mt], bfr[nt], acc[mt][nt], 0, 0, 0);
        }
        __syncthreads();
    }

    #pragma unroll
    for (int mt = 0; mt < 2; mt++) {
        #pragma unroll
        for (int reg = 0; reg < 4; reg++) {
            int m = m0 + wr + mt * 16 + quad * 4 + reg;
            #pragma unroll
            for (int nt = 0; nt < 4; nt++) {
                int n = n0 + wc + nt * 16 + l15;
                outF[(size_t)m * En + n] = acc[mt][nt][reg] + bias[n];
            }
        }
    }
}

// ---------------------------------------------------------------------------
// Flash attention, round-14: r8 body with ADJACENT q-tile pairing {2k,2k+1}.
// r8's {i,31-i} pairing balanced MFMA work but wasted staging: for
// kt in (i,31-i] only one frag computes, yet a full K/V tile is staged.
// Total staging rounds 25088. Adjacent pairing {2k,2k+1}: both frags
// active in all rounds except the last -> 17408 rounds (-31%), identical
// compute/LDS/VGPR. Block lengths now 2..32; dispatch order interleaves
// long+short (k sequence 15,0,14,1,...: consecutive pairs sum to 34
// rounds) so each CU hosts a balanced mix of its 4 resident blocks.
// XCD co-location kept (bh's blocks on one XCD; K/V L2-resident).
// __launch_bounds__(256,8) pin kept (body fits 56 VGPR; r9/r10: pin only
// valid when natural use <= 64). r13's single-frag variant REGRESSED
// (70.6us: +35% staging rounds) - do not un-pair.
// ---------------------------------------------------------------------------
__global__ __launch_bounds__(256, 8) void attn_mfma_kernel(
    const short* __restrict__ Q, const short* __restrict__ K,
    const short* __restrict__ Vt, short* __restrict__ Cb)
{
    constexpr int PP = 72;                  // Ps pitch in shorts
    const int bid  = blockIdx.x;            // 0..1023
    const int slot = bid & 7;               // XCD (dispatch round-robin)
    const int j    = bid >> 3;              // 0..127 within XCD
    const int bh   = slot * 8 + (j & 7);    // 8 bh per XCD
    const int ko   = j >> 3;                // 0..15 dispatch-order slot
    const int k    = (ko & 1) ? (ko >> 1) : (15 - (ko >> 1));  // 15,0,14,1,...
    const int b = bh >> 4, h = bh & 15;
    const int t0 = 2 * k, t1 = 2 * k + 1;   // adjacent q-tiles

    __shared__ short Ks[64 * 64];           // [kv][d], swizzled
    __shared__ short Vts[64 * 64];          // [d][kv], swizzled
    __shared__ short Ps[128 * PP];          // [f*64 + q][kv]
    __shared__ float l_sh[128];

    const int tid  = threadIdx.x;
    const int w    = tid >> 6;
    const int lane = tid & 63;
    const int quad = lane >> 4;
    const int l15  = lane & 15;

    const short* Kp = K + (size_t)bh * Sn * Dn;
    const short* Vp = Vt + (size_t)bh * Dn * Sn;

    const int tf[2] = {t0, t1};
    s16x8 aq[2][2];
    #pragma unroll
    for (int f = 0; f < 2; f++)
        #pragma unroll
        for (int ks = 0; ks < 2; ks++)
            aq[f][ks] = *(const s16x8*)(
                Q + ((size_t)bh * Sn + tf[f] * 64 + w * 16 + l15) * Dn +
                ks * 32 + quad * 8);

    f32x4 acc[2][4];
    #pragma unroll
    for (int f = 0; f < 2; f++)
        #pragma unroll
        for (int nt = 0; nt < 4; nt++)
            #pragma unroll
            for (int e = 0; e < 4; e++) acc[f][nt][e] = 0.f;
    float lpart[2] = {0.f, 0.f};

    for (int kt = 0; kt <= t1; kt++) {
        // stage K/Vt tiles (swizzled)
        #pragma unroll
        for (int r = 0; r < 2; r++) {
            int c   = (r * 4 + w) * 64 + lane;
            int row = c >> 3;
            int lp  = (c & 7) ^ (row & 7);
            glds16(Kp + (size_t)(kt * 64 + row) * Dn + lp * 8,
                   Ks + (r * 4 + w) * 512);
            glds16(Vp + (size_t)row * Sn + kt * 64 + lp * 8,
                   Vts + (r * 4 + w) * 512);
        }
        __syncthreads();

        // per frag: St = K @ Q^T, exp2, pack, write P
        #pragma unroll
        for (int f = 0; f < 2; f++) {
            if (kt > tf[f]) continue;
            f32x4 st[4];
            #pragma unroll
            for (int nt = 0; nt < 4; nt++)
                #pragma unroll
                for (int e = 0; e < 4; e++) st[nt][e] = 0.f;
            #pragma unroll
            for (int ks = 0; ks < 2; ks++) {
                #pragma unroll
                for (int nt = 0; nt < 4; nt++) {
                    s16x8 bk = *(const s16x8*)&Ks[(nt * 16 + l15) * 64 +
                                                  (((ks * 4 + quad) ^ (l15 & 7)) * 8)];
                    st[nt] = __builtin_amdgcn_mfma_f32_16x16x32_bf16(
                        bk, aq[f][ks], st[nt], 0, 0, 0);
                }
            }
            // St rows kv = nt*16+quad*4+reg, col q = w*16+l15 (local)
            const bool diag = (kt == tf[f]);
            #pragma unroll
            for (int nt = 0; nt < 4; nt++) {
                float v[4];
                #pragma unroll
                for (int reg = 0; reg < 4; reg++) {
                    float e = __builtin_amdgcn_exp2f(st[nt][reg]);
                    if (diag && (nt * 16 + quad * 4 + reg) > (w * 16 + l15))
                        e = 0.f;
                    v[reg] = e;
                    lpart[f] += e;
                }
                uint2 pk;
                pk.x = cvt_pk_bf16(v[0], v[1]);
                pk.y = cvt_pk_bf16(v[2], v[3]);
                *(uint2*)&Ps[(f * 64 + w * 16 + l15) * PP + nt * 16 + quad * 4] = pk;
            }
        }

        // PV: O += P @ V
        #pragma unroll
        for (int ks = 0; ks < 2; ks++) {
            s16x8 bv[4];
            #pragma unroll
            for (int nt = 0; nt < 4; nt++)
                bv[nt] = *(const s16x8*)&Vts[(nt * 16 + l15) * 64 +
                                             (((ks * 4 + quad) ^ (l15 & 7)) * 8)];
            #pragma unroll
            for (int f = 0; f < 2; f++) {
                if (kt > tf[f]) continue;
                s16x8 ap = *(const s16x8*)&Ps[(f * 64 + w * 16 + l15) * PP +
                                              ks * 32 + quad * 8];
                #pragma unroll
                for (int nt = 0; nt < 4; nt++)
                    acc[f][nt] = __builtin_amdgcn_mfma_f32_16x16x32_bf16(
                        ap, bv[nt], acc[f][nt], 0, 0, 0);
            }
        }
        __syncthreads();
    }

    // finalize l and publish per-row
    #pragma unroll
    for (int f = 0; f < 2; f++) {
        float l = lpart[f];
        l += __shfl_xor(l, 16);
        l += __shfl_xor(l, 32);
        if (quad == 0) l_sh[f * 64 + w * 16 + l15] = l;
    }
    __syncthreads();

    // epilogue: conc[b][s][h*64+d] bf16
    #pragma unroll
    for (int f = 0; f < 2; f++) {
        #pragma unroll
        for (int reg = 0; reg < 4; reg++) {
            int s = tf[f] * 64 + w * 16 + quad * 4 + reg;
            float inv = 1.f / l_sh[f * 64 + w * 16 + quad * 4 + reg];
            #pragma unroll
            for (int nt = 0; nt < 4; nt++) {
                int d = nt * 16 + l15;
                Cb[((size_t)(b * Sn + s)) * En + h * Dn + d] =
                    f2bf(acc[f][nt][reg] * inv);
            }
        }
    }
}

// ---------------------------------------------------------------------------
extern "C" void kernel_launch(void* const* d_in, const int* in_sizes, int n_in,
                              void* d_out, int out_size, void* d_ws, size_t ws_size,
                              hipStream_t stream) {
    const float* x  = (const float*)d_in[0];
    const float* Wq = (const float*)d_in[1];
    const float* bq = (const float*)d_in[2];
    const float* Wk = (const float*)d_in[3];
    const float* bk = (const float*)d_in[4];
    const float* Wv = (const float*)d_in[5];
    const float* bv = (const float*)d_in[6];
    const float* Wo = (const float*)d_in[7];
    const float* bo = (const float*)d_in[8];
    float* out = (float*)d_out;

    const size_t XS   = (size_t)Bn * Sn * En;       // 8,388,608
    const size_t WCS  = (size_t)3 * En * Hn * Dn;   // 3,145,728
    const size_t WOS  = (size_t)En * En;            // 1,048,576
    const size_t QSZ  = (size_t)Bn * Hn * Sn * Dn;  // 8,388,608

    short* Ax    = (short*)d_ws;
    short* Wcat  = Ax + XS;
    short* Wob   = Wcat + WCS;
    float* biasc = (float*)(Wob + WOS);
    short* Qb    = (short*)(biasc + 3072);
    short* Kb    = Qb + QSZ;
    short* Vtb   = Kb + QSZ;
    short* Cbf   = Vtb + QSZ;

    // fused prep: conv_x (8192 blocks) + build_wcat (768) + conv_wo (1024)
    prep_kernel<<<dim3(8192 + 768 + 1024), 256, 0, stream>>>(
        x, Ax, Wq, bq, Wk, bk, Wv, bv, Wcat, biasc, Wo, Wob);

    // QKV: [8192 x 1024] @ [1024 x 3072]
    gemm_bt_kernel<<<dim3((Bn * Sn) / 256, 3072 / 128), 512, 0, stream>>>(
        Ax, Wcat, biasc, nullptr, Qb, Kb, Vtb, 1);

    // attn: 1024 blocks, adjacent q-tile pairs, interleaved-length dispatch
    attn_mfma_kernel<<<dim3(16 * Bn * Hn), 256, 0, stream>>>(Qb, Kb, Vtb, Cbf);

    // out: [8192 x 1024] @ Wo^T + bo  (r8's 128x128, 512 blocks)
    gemm_bt_out_kernel<<<dim3((Bn * Sn) / 128, En / 128), 512, 0, stream>>>(
        Cbf, Wob, bo, out);
}

// Round 15
// 241.549 us; speedup vs baseline: 1.0532x; 1.0532x over previous
//
#include <hip/hip_runtime.h>
#include <math.h>

// B=4, S=2048, E=1024, H=16, D=64
constexpr int Bn = 4;
constexpr int Sn = 2048;
constexpr int En = 1024;
constexpr int Hn = 16;
constexpr int Dn = 64;

typedef float f32x4 __attribute__((ext_vector_type(4)));
typedef short s16x8 __attribute__((ext_vector_type(8)));
typedef short s16x4 __attribute__((ext_vector_type(4)));

__device__ __forceinline__ short f2bf(float f) {
    unsigned u = __builtin_bit_cast(unsigned, f);
    unsigned r = (u + 0x7fffu + ((u >> 16) & 1u)) >> 16;
    return (short)r;
}

// pack two f32 -> two bf16 (RNE) in one VALU op
__device__ __forceinline__ unsigned cvt_pk_bf16(float lo, float hi) {
    unsigned r;
    asm("v_cvt_pk_bf16_f32 %0, %1, %2" : "=v"(r) : "v"(lo), "v"(hi));
    return r;
}

// async global->LDS, 16B per lane; LDS dest = wave-uniform base + lane*16
__device__ __forceinline__ void glds16(const short* g, short* l) {
    __builtin_amdgcn_global_load_lds(
        (const __attribute__((address_space(1))) short*)g,
        (__attribute__((address_space(3))) short*)l, 16, 0, 0);
}

// ---------------------------------------------------------------------------
// Fused prep kernel: one dispatch replaces conv_x / build_wcat / conv_wo.
// Blocks [0,8192): x f32 -> bf16. [8192,8960): Wcat transpose. [8960,9984): Wo.
// ---------------------------------------------------------------------------
__global__ __launch_bounds__(256) void prep_kernel(
    const float* __restrict__ x, short* __restrict__ y,
    const float* __restrict__ Wq, const float* __restrict__ bq,
    const float* __restrict__ Wk, const float* __restrict__ bk,
    const float* __restrict__ Wv, const float* __restrict__ bv,
    short* __restrict__ Wcat, float* __restrict__ bias_cat,
    const float* __restrict__ Wo, short* __restrict__ Wob)
{
    const int bid = blockIdx.x;
    const int tid = threadIdx.x;

    if (bid < 8192) {
        // conv_x
        size_t i = ((size_t)bid * 256 + tid) * 4;
        float4 v = *(const float4*)(x + i);
        s16x4 o;
        o[0] = f2bf(v.x); o[1] = f2bf(v.y); o[2] = f2bf(v.z); o[3] = f2bf(v.w);
        *(s16x4*)(y + i) = o;
    } else if (bid < 8960) {
        // build_wcat: j = et + h*16 + p*256
        const int j  = bid - 8192;
        const int et = j & 15, h = (j >> 4) & 15, p = j >> 8;
        const float* W  = (p == 0) ? Wq : (p == 1) ? Wk : Wv;
        const float* bb = (p == 0) ? bq : (p == 1) ? bk : bv;
        const float* Wh = W + (size_t)h * En * Dn;

        __shared__ float T[64][65];
        #pragma unroll
        for (int it = 0; it < 16; it++) {
            int idx = tid + it * 256;
            int e = idx >> 6, d = idx & 63;
            T[d][e] = Wh[(size_t)(et * 64 + e) * Dn + d];
        }
        __syncthreads();
        #pragma unroll
        for (int it = 0; it < 16; it++) {
            int idx = tid + it * 256;
            int d = idx >> 6, e = idx & 63;
            Wcat[(size_t)(p * 1024 + h * 64 + d) * En + et * 64 + e] = f2bf(T[d][e]);
        }
        if (et == 0 && tid < 64)
            bias_cat[p * 1024 + h * 64 + tid] = bb[h * 64 + tid];
    } else {
        // conv_wo
        const size_t base = (size_t)(bid - 8960) * En;
        #pragma unroll
        for (int i = 0; i < 4; i++) {
            int k = tid + i * 256;
            Wob[base + k] = f2bf(Wo[base + k]);
        }
    }
}

// ---------------------------------------------------------------------------
// bf16 MFMA GEMM: C[M x N] = A[M x 1024] @ Bt[N x 1024]^T (+ bias)
// 256x128 tile, 8 waves (512 thr), BK=64, global_load_lds, XOR-swizzled LDS.
// Each wave: 64x64 subtile (wr = (w>>1)*64 in M, wc = (w&1)*64 in N).
// mode 0: fp32 out + bias. mode 1: QKV epilogue (Q scaled by log2e/8; V packed).
// ---------------------------------------------------------------------------
__global__ __launch_bounds__(512) void gemm_bt_kernel(
    const short* __restrict__ A,
    const short* __restrict__ Bt,
    const float* __restrict__ bias,
    float* __restrict__ outF,
    short* __restrict__ Qb, short* __restrict__ Kb, short* __restrict__ Vtb,
    int mode)
{
    constexpr int K = En;
    const int m0 = blockIdx.x * 256;
    const int n0 = blockIdx.y * 128;

    __shared__ short As[256 * 64];   // 32 KB
    __shared__ short Bs[128 * 64];   // 16 KB

    const int tid  = threadIdx.x;
    const int w    = tid >> 6;       // 0..7
    const int lane = tid & 63;
    const int quad = lane >> 4;
    const int l15  = lane & 15;
    const int wr = (w >> 1) * 64;    // 0,64,128,192
    const int wc = (w & 1) * 64;     // 0,64

    f32x4 acc[4][4];
    #pragma unroll
    for (int i = 0; i < 4; i++)
        #pragma unroll
        for (int j = 0; j < 4; j++)
            #pragma unroll
            for (int e = 0; e < 4; e++) acc[i][j][e] = 0.f;

    for (int k0 = 0; k0 < K; k0 += 64) {
        // A: 256 rows x 64 shorts = 2048 chunks; 4 wave-issues per wave
        #pragma unroll
        for (int r = 0; r < 4; r++) {
            int c   = (r * 8 + w) * 64 + lane;
            int row = c >> 3;
            int lp  = (c & 7) ^ (row & 7);
            glds16(A + (size_t)(m0 + row) * K + k0 + lp * 8,
                   As + (r * 8 + w) * 512);
        }
        // B: 128 rows = 1024 chunks; 2 wave-issues per wave
        #pragma unroll
        for (int r = 0; r < 2; r++) {
            int c   = (r * 8 + w) * 64 + lane;
            int row = c >> 3;
            int lp  = (c & 7) ^ (row & 7);
            glds16(Bt + (size_t)(n0 + row) * K + k0 + lp * 8,
                   Bs + (r * 8 + w) * 512);
        }
        __syncthreads();

        #pragma unroll
        for (int ks = 0; ks < 2; ks++) {
            s16x8 af[4], bfr[4];
            #pragma unroll
            for (int mt = 0; mt < 4; mt++) {
                int row = wr + mt * 16 + l15;
                af[mt] = *(const s16x8*)&As[row * 64 + (((ks * 4 + quad) ^ (l15 & 7)) * 8)];
            }
            #pragma unroll
            for (int nt = 0; nt < 4; nt++) {
                int row = wc + nt * 16 + l15;
                bfr[nt] = *(const s16x8*)&Bs[row * 64 + (((ks * 4 + quad) ^ (l15 & 7)) * 8)];
            }
            #pragma unroll
            for (int mt = 0; mt < 4; mt++)
                #pragma unroll
                for (int nt = 0; nt < 4; nt++)
                    acc[mt][nt] = __builtin_amdgcn_mfma_f32_16x16x32_bf16(
                        af[mt], bfr[nt], acc[mt][nt], 0, 0, 0);
        }
        __syncthreads();
    }

    if (mode == 0) {
        #pragma unroll
        for (int mt = 0; mt < 4; mt++) {
            #pragma unroll
            for (int reg = 0; reg < 4; reg++) {
                int m = m0 + wr + mt * 16 + quad * 4 + reg;
                #pragma unroll
                for (int nt = 0; nt < 4; nt++) {
                    int n = n0 + wc + nt * 16 + l15;
                    outF[(size_t)m * En + n] = acc[mt][nt][reg] + bias[n];
                }
            }
        }
    } else {
        const int p = (n0 + wc) >> 10;   // uniform over 64-wide wave tile
        if (p < 2) {
            // fold 1/sqrt(D) AND log2(e) into Q so attn can use exp2 directly
            const float qs = (p == 0) ? 0.125f * 1.44269504088896f : 1.0f;
            short* dst = (p == 0) ? Qb : Kb;
            #pragma unroll
            for (int mt = 0; mt < 4; mt++) {
                #pragma unroll
                for (int reg = 0; reg < 4; reg++) {
                    int m = m0 + wr + mt * 16 + quad * 4 + reg;
                    int b = m >> 11, s = m & 2047;
                    #pragma unroll
                    for (int nt = 0; nt < 4; nt++) {
                        int n = n0 + wc + nt * 16 + l15;
                        int h = (n >> 6) & 15, d = n & 63;
                        dst[(((size_t)(b * Hn + h)) * Sn + s) * Dn + d] =
                            f2bf((acc[mt][nt][reg] + bias[n]) * qs);
                    }
                }
            }
        } else {
            // V: regs 0..3 are contiguous in s -> one 8B store per (mt,nt)
            #pragma unroll
            for (int mt = 0; mt < 4; mt++) {
                int m = m0 + wr + mt * 16 + quad * 4;   // reg 0; same b for all 4
                int b = m >> 11, s = m & 2047;
                #pragma unroll
                for (int nt = 0; nt < 4; nt++) {
                    int n = n0 + wc + nt * 16 + l15;
                    int h = (n >> 6) & 15, d = n & 63;
                    s16x4 pk;
                    #pragma unroll
                    for (int reg = 0; reg < 4; reg++)
                        pk[reg] = f2bf(acc[mt][nt][reg] + bias[n]);
                    *(s16x4*)(Vtb + (((size_t)(b * Hn + h)) * Dn + d) * Sn + s) = pk;
                }
            }
        }
    }
}

// ---------------------------------------------------------------------------
// Out-projection GEMM: 128x128 tile, 512 thr (8 waves x 32x64 subtile).
// EXACT r8 version (best measured total). NO pin (natural ~70 VGPR; r10
// proved pinning past natural use spills). Do not touch.
// ---------------------------------------------------------------------------
__global__ __launch_bounds__(512) void gemm_bt_out_kernel(
    const short* __restrict__ A,
    const short* __restrict__ Bt,
    const float* __restrict__ bias,
    float* __restrict__ outF)
{
    constexpr int K = En;
    const int m0 = blockIdx.x * 128;
    const int n0 = blockIdx.y * 128;

    __shared__ short As[128 * 64];   // 16 KB
    __shared__ short Bs[128 * 64];   // 16 KB

    const int tid  = threadIdx.x;
    const int w    = tid >> 6;       // 0..7
    const int lane = tid & 63;
    const int quad = lane >> 4;
    const int l15  = lane & 15;
    const int wr = (w >> 1) * 32;    // 0,32,64,96
    const int wc = (w & 1) * 64;     // 0,64

    f32x4 acc[2][4];
    #pragma unroll
    for (int i = 0; i < 2; i++)
        #pragma unroll
        for (int j = 0; j < 4; j++)
            #pragma unroll
            for (int e = 0; e < 4; e++) acc[i][j][e] = 0.f;

    for (int k0 = 0; k0 < K; k0 += 64) {
        // A: 128 rows x 64 shorts = 1024 chunks; 2 wave-issues per wave
        #pragma unroll
        for (int r = 0; r < 2; r++) {
            int c   = (r * 8 + w) * 64 + lane;
            int row = c >> 3;
            int lp  = (c & 7) ^ (row & 7);
            glds16(A + (size_t)(m0 + row) * K + k0 + lp * 8,
                   As + (r * 8 + w) * 512);
        }
        // B: 128 rows = 1024 chunks; 2 wave-issues per wave
        #pragma unroll
        for (int r = 0; r < 2; r++) {
            int c   = (r * 8 + w) * 64 + lane;
            int row = c >> 3;
            int lp  = (c & 7) ^ (row & 7);
            glds16(Bt + (size_t)(n0 + row) * K + k0 + lp * 8,
                   Bs + (r * 8 + w) * 512);
        }
        __syncthreads();

        #pragma unroll
        for (int ks = 0; ks < 2; ks++) {
            s16x8 af[2], bfr[4];
            #pragma unroll
            for (int mt = 0; mt < 2; mt++) {
                int row = wr + mt * 16 + l15;
                af[mt] = *(const s16x8*)&As[row * 64 + (((ks * 4 + quad) ^ (l15 & 7)) * 8)];
            }
            #pragma unroll
            for (int nt = 0; nt < 4; nt++) {
                int row = wc + nt * 16 + l15;
                bfr[nt] = *(const s16x8*)&Bs[row * 64 + (((ks * 4 + quad) ^ (l15 & 7)) * 8)];
            }
            #pragma unroll
            for (int mt = 0; mt < 2; mt++)
                #pragma unroll
                for (int nt = 0; nt < 4; nt++)
                    acc[mt][nt] = __builtin_amdgcn_mfma_f32_16x16x32_bf16(
                        af[mt], bfr[nt], acc[mt][nt], 0, 0, 0);
        }
        __syncthreads();
    }

    #pragma unroll
    for (int mt = 0; mt < 2; mt++) {
        #pragma unroll
        for (int reg = 0; reg < 4; reg++) {
            int m = m0 + wr + mt * 16 + quad * 4 + reg;
            #pragma unroll
            for (int nt = 0; nt < 4; nt++) {
                int n = n0 + wc + nt * 16 + l15;
                outF[(size_t)m * En + n] = acc[mt][nt][reg] + bias[n];
            }
        }
    }
}

// ---------------------------------------------------------------------------
// Flash attention — r8 winner restored (66.4us, 56 VGPR, 32% occ, FETCH
// 24.6MB), plus ONE register-neutral micro-fix: lpart tree-sum (serial
// dependent-add chain 16 -> 4 per frag-iter; temps fold into existing v[]).
// bf16 MFMA, static-max softmax, balanced causal pairing {i, 31-i}.
// S^T via swapped MFMA; exp2-direct (log2e folded into Q); cvt_pk packing;
// XCD co-location swizzle; __launch_bounds__(256,8) pin (valid: body fits
// 56 VGPR). Structural variants all regressed: r9 dbuf (+LDS/VGPR, 80us),
// r13 un-pair (+35% staging, 71us), r14 adjacent-pair (occ decay, 72us).
// This 2-barrier structure at 4 blocks/CU is the measured local optimum.
// ---------------------------------------------------------------------------
__global__ __launch_bounds__(256, 8) void attn_mfma_kernel(
    const short* __restrict__ Q, const short* __restrict__ K,
    const short* __restrict__ Vt, short* __restrict__ Cb)
{
    constexpr int PP = 72;                  // Ps pitch in shorts
    const int bid = blockIdx.x;             // 0..1023
    const int kk  = bid >> 3;               // 0..127
    const int bh  = (bid & 7) * 8 + (kk >> 4);  // 8 bh per XCD
    const int i   = kk & 15;                // 0..15
    const int b = bh >> 4, h = bh & 15;
    const int t0 = i, t1 = 31 - i;          // frag q-tile indices

    __shared__ short Ks[64 * 64];           // [kv][d], swizzled
    __shared__ short Vts[64 * 64];          // [d][kv], swizzled
    __shared__ short Ps[128 * PP];          // [f*64 + q][kv]
    __shared__ float l_sh[128];

    const int tid  = threadIdx.x;
    const int w    = tid >> 6;
    const int lane = tid & 63;
    const int quad = lane >> 4;
    const int l15  = lane & 15;

    const short* Kp = K + (size_t)bh * Sn * Dn;
    const short* Vp = Vt + (size_t)bh * Dn * Sn;

    const int tf[2] = {t0, t1};
    s16x8 aq[2][2];
    #pragma unroll
    for (int f = 0; f < 2; f++)
        #pragma unroll
        for (int ks = 0; ks < 2; ks++)
            aq[f][ks] = *(const s16x8*)(
                Q + ((size_t)bh * Sn + tf[f] * 64 + w * 16 + l15) * Dn +
                ks * 32 + quad * 8);

    f32x4 acc[2][4];
    #pragma unroll
    for (int f = 0; f < 2; f++)
        #pragma unroll
        for (int nt = 0; nt < 4; nt++)
            #pragma unroll
            for (int e = 0; e < 4; e++) acc[f][nt][e] = 0.f;
    float lpart[2] = {0.f, 0.f};

    for (int kt = 0; kt <= t1; kt++) {
        // stage K/Vt tiles (swizzled)
        #pragma unroll
        for (int r = 0; r < 2; r++) {
            int c   = (r * 4 + w) * 64 + lane;
            int row = c >> 3;
            int lp  = (c & 7) ^ (row & 7);
            glds16(Kp + (size_t)(kt * 64 + row) * Dn + lp * 8,
                   Ks + (r * 4 + w) * 512);
            glds16(Vp + (size_t)row * Sn + kt * 64 + lp * 8,
                   Vts + (r * 4 + w) * 512);
        }
        __syncthreads();

        // per frag: St = K @ Q^T, exp2, pack, write P
        #pragma unroll
        for (int f = 0; f < 2; f++) {
            if (kt > tf[f]) continue;
            f32x4 st[4];
            #pragma unroll
            for (int nt = 0; nt < 4; nt++)
                #pragma unroll
                for (int e = 0; e < 4; e++) st[nt][e] = 0.f;
            #pragma unroll
            for (int ks = 0; ks < 2; ks++) {
                #pragma unroll
                for (int nt = 0; nt < 4; nt++) {
                    s16x8 bk = *(const s16x8*)&Ks[(nt * 16 + l15) * 64 +
                                                  (((ks * 4 + quad) ^ (l15 & 7)) * 8)];
                    st[nt] = __builtin_amdgcn_mfma_f32_16x16x32_bf16(
                        bk, aq[f][ks], st[nt], 0, 0, 0);
                }
            }
            // St rows kv = nt*16+quad*4+reg, col q = w*16+l15 (local)
            const bool diag = (kt == tf[f]);
            #pragma unroll
            for (int nt = 0; nt < 4; nt++) {
                float v[4];
                #pragma unroll
                for (int reg = 0; reg < 4; reg++) {
                    float e = __builtin_amdgcn_exp2f(st[nt][reg]);
                    if (diag && (nt * 16 + quad * 4 + reg) > (w * 16 + l15))
                        e = 0.f;
                    v[reg] = e;
                }
                lpart[f] += (v[0] + v[1]) + (v[2] + v[3]);   // tree: 1 dep-add/nt
                uint2 pk;
                pk.x = cvt_pk_bf16(v[0], v[1]);
                pk.y = cvt_pk_bf16(v[2], v[3]);
                *(uint2*)&Ps[(f * 64 + w * 16 + l15) * PP + nt * 16 + quad * 4] = pk;
            }
        }

        // PV: O += P @ V
        #pragma unroll
        for (int ks = 0; ks < 2; ks++) {
            s16x8 bv[4];
            #pragma unroll
            for (int nt = 0; nt < 4; nt++)
                bv[nt] = *(const s16x8*)&Vts[(nt * 16 + l15) * 64 +
                                             (((ks * 4 + quad) ^ (l15 & 7)) * 8)];
            #pragma unroll
            for (int f = 0; f < 2; f++) {
                if (kt > tf[f]) continue;
                s16x8 ap = *(const s16x8*)&Ps[(f * 64 + w * 16 + l15) * PP +
                                              ks * 32 + quad * 8];
                #pragma unroll
                for (int nt = 0; nt < 4; nt++)
                    acc[f][nt] = __builtin_amdgcn_mfma_f32_16x16x32_bf16(
                        ap, bv[nt], acc[f][nt], 0, 0, 0);
            }
        }
        __syncthreads();
    }

    // finalize l and publish per-row
    #pragma unroll
    for (int f = 0; f < 2; f++) {
        float l = lpart[f];
        l += __shfl_xor(l, 16);
        l += __shfl_xor(l, 32);
        if (quad == 0) l_sh[f * 64 + w * 16 + l15] = l;
    }
    __syncthreads();

    // epilogue: conc[b][s][h*64+d] bf16
    #pragma unroll
    for (int f = 0; f < 2; f++) {
        #pragma unroll
        for (int reg = 0; reg < 4; reg++) {
            int s = tf[f] * 64 + w * 16 + quad * 4 + reg;
            float inv = 1.f / l_sh[f * 64 + w * 16 + quad * 4 + reg];
            #pragma unroll
            for (int nt = 0; nt < 4; nt++) {
                int d = nt * 16 + l15;
                Cb[((size_t)(b * Sn + s)) * En + h * Dn + d] =
                    f2bf(acc[f][nt][reg] * inv);
            }
        }
    }
}

// ---------------------------------------------------------------------------
extern "C" void kernel_launch(void* const* d_in, const int* in_sizes, int n_in,
                              void* d_out, int out_size, void* d_ws, size_t ws_size,
                              hipStream_t stream) {
    const float* x  = (const float*)d_in[0];
    const float* Wq = (const float*)d_in[1];
    const float* bq = (const float*)d_in[2];
    const float* Wk = (const float*)d_in[3];
    const float* bk = (const float*)d_in[4];
    const float* Wv = (const float*)d_in[5];
    const float* bv = (const float*)d_in[6];
    const float* Wo = (const float*)d_in[7];
    const float* bo = (const float*)d_in[8];
    float* out = (float*)d_out;

    const size_t XS   = (size_t)Bn * Sn * En;       // 8,388,608
    const size_t WCS  = (size_t)3 * En * Hn * Dn;   // 3,145,728
    const size_t WOS  = (size_t)En * En;            // 1,048,576
    const size_t QSZ  = (size_t)Bn * Hn * Sn * Dn;  // 8,388,608

    short* Ax    = (short*)d_ws;
    short* Wcat  = Ax + XS;
    short* Wob   = Wcat + WCS;
    float* biasc = (float*)(Wob + WOS);
    short* Qb    = (short*)(biasc + 3072);
    short* Kb    = Qb + QSZ;
    short* Vtb   = Kb + QSZ;
    short* Cbf   = Vtb + QSZ;

    // fused prep: conv_x (8192 blocks) + build_wcat (768) + conv_wo (1024)
    prep_kernel<<<dim3(8192 + 768 + 1024), 256, 0, stream>>>(
        x, Ax, Wq, bq, Wk, bk, Wv, bv, Wcat, biasc, Wo, Wob);

    // QKV: [8192 x 1024] @ [1024 x 3072]
    gemm_bt_kernel<<<dim3((Bn * Sn) / 256, 3072 / 128), 512, 0, stream>>>(
        Ax, Wcat, biasc, nullptr, Qb, Kb, Vtb, 1);

    attn_mfma_kernel<<<dim3(16 * Bn * Hn), 256, 0, stream>>>(Qb, Kb, Vtb, Cbf);

    // out: [8192 x 1024] @ Wo^T + bo  (r8's 128x128, 512 blocks)
    gemm_bt_out_kernel<<<dim3((Bn * Sn) / 128, En / 128), 512, 0, stream>>>(
        Cbf, Wob, bo, out);
}